// Round 18
// baseline (628.295 us; speedup 1.0000x reference)
//
#include <hip/hip_runtime.h>

// Gaussian pyramid, 4 levels. Input (16,3,1024,1024) f32.
// R18: ONE-SHOT per output row (no per-thread row loop). Six rounds of
// counters show: loop kernels write 2-9x phantom HBM (scratch-backed state,
// scales with R); one-shot kernels are write-clean (R1: exact, R5: ~ideal).
// 2px/lane makes every store dense (R12: 4px/lane copy stores at 32B stride
// added ~170MB). (64,4) blocks, branchless edge remap, fused level-0 copy.

struct R12f { float4 A, B, C; };            // 12 consecutive input floats
struct W7 { float w0, w1, w2, w3, w4, w5, w6; float4 cp; };

template <int WIN>
__device__ __forceinline__ R12f load3(const float* ip, int iy, int xb) {
    const float4* p = (const float4*)(ip + (size_t)iy * WIN + xb);
    R12f r; r.A = p[0]; r.B = p[1]; r.C = p[2];
    return r;
}

// Window w0..w6 = input x = 4g-2 .. 4g+4 (replicate-clamped); cp = owned
// floats [4g, 4g+4). interior xb=4g-4: w=[A.z,A.w,B.x,B.y,B.z,B.w,C.x], cp=B
// L (g==0, xb=0): w=[A.x,A.x,A.x,A.y,A.z,A.w,B.x], cp=A
// Rr (g==GMAX, xb=4g-8): w=[B.z,B.w,C.x,C.y,C.z,C.w,C.w], cp=C
__device__ __forceinline__ W7 extract(const R12f& r, bool L, bool Rr) {
    W7 o;
    o.w0 = L ? r.A.x : (Rr ? r.B.z : r.A.z);
    o.w1 = L ? r.A.x : (Rr ? r.B.w : r.A.w);
    o.w2 = L ? r.A.x : (Rr ? r.C.x : r.B.x);
    o.w3 = L ? r.A.y : (Rr ? r.C.y : r.B.y);
    o.w4 = L ? r.A.z : (Rr ? r.C.z : r.B.z);
    o.w5 = L ? r.A.w : (Rr ? r.C.w : r.B.w);
    o.w6 = L ? r.B.x : (Rr ? r.C.w : r.C.x);
    o.cp.x = o.w2; o.cp.y = o.w3; o.cp.z = o.w4; o.cp.w = o.w5;
    return o;
}

__device__ __forceinline__ float2 hconv2(const W7& w) {
    const float k0 = 0.0625f, k1 = 0.25f, k2 = 0.375f;
    float2 h;
    h.x = k0 * (w.w0 + w.w4) + k1 * (w.w1 + w.w3) + k2 * w.w2;   // out x=2g
    h.y = k0 * (w.w2 + w.w6) + k1 * (w.w3 + w.w5) + k2 * w.w4;   // out x=2g+1
    return h;
}

template <int HIN, int WIN, bool FUSE>
__global__ __launch_bounds__(256) void gpyr_once(
        const float* __restrict__ in,
        float* __restrict__ out0,
        float* __restrict__ out1) {
    constexpr int HOUT = HIN / 2, WOUT = WIN / 2;
    constexpr int GMAX = WIN / 4 - 1;
    const int tx = threadIdx.x, ty = threadIdx.y;
    const int g  = blockIdx.x * 64 + tx;       // lane's x-group (4 input floats)
    const int oy = blockIdx.y * 4 + ty;        // one output row per thread
    const int img = blockIdx.z;

    const bool L  = (g == 0);
    const bool Rr = (g == GMAX);
    int xb = 4 * g - 4;
    if (L)  xb = 0;
    if (Rr) xb = 4 * g - 8;

    const float* ip = in + (size_t)img * HIN * WIN;

    // 5-row window (replicate-clamped rows). All 15 loads independent.
    R12f r0 = load3<WIN>(ip, max(2 * oy - 2, 0), xb);
    R12f r1 = load3<WIN>(ip, max(2 * oy - 1, 0), xb);
    R12f r2 = load3<WIN>(ip, 2 * oy, xb);
    R12f r3 = load3<WIN>(ip, 2 * oy + 1, xb);                  // <= HIN-1 always
    R12f r4 = load3<WIN>(ip, min(2 * oy + 2, HIN - 1), xb);

    const float k0 = 0.0625f, k1 = 0.25f, k2 = 0.375f;

    W7 e0 = extract(r0, L, Rr); float2 h0 = hconv2(e0);
    W7 e1 = extract(r1, L, Rr); float2 h1 = hconv2(e1);
    W7 e2 = extract(r2, L, Rr); float2 h2 = hconv2(e2);
    W7 e3 = extract(r3, L, Rr); float2 h3 = hconv2(e3);
    W7 e4 = extract(r4, L, Rr); float2 h4 = hconv2(e4);

    if (FUSE) {
        float* o0 = out0 + (size_t)img * HIN * WIN;
        *(float4*)(o0 + (size_t)(2 * oy) * WIN + 4 * g)     = e2.cp;  // dense 16B/lane
        *(float4*)(o0 + (size_t)(2 * oy + 1) * WIN + 4 * g) = e3.cp;
    }

    float2 o;
    o.x = k0 * (h0.x + h4.x) + k1 * (h1.x + h3.x) + k2 * h2.x;
    o.y = k0 * (h0.y + h4.y) + k1 * (h1.y + h3.y) + k2 * h2.y;
    float* o1 = out1 + (size_t)img * HOUT * WOUT;
    *(float2*)(o1 + (size_t)oy * WOUT + 2 * g) = o;                   // dense 8B/lane
}

extern "C" void kernel_launch(void* const* d_in, const int* in_sizes, int n_in,
                              void* d_out, int out_size, void* d_ws, size_t ws_size,
                              hipStream_t stream) {
    const float* im = (const float*)d_in[0];
    float* out = (float*)d_out;

    const int NC = 16 * 3;
    const size_t L0 = (size_t)NC * 1024 * 1024;
    const size_t L1 = (size_t)NC * 512 * 512;
    const size_t L2 = (size_t)NC * 256 * 256;

    float* out0 = out;
    float* out1 = out0 + L0;
    float* out2 = out1 + L1;
    float* out3 = out2 + L2;

    // Level 0+1 fused: 512 out rows, 2px/lane -> grid (4, 128, 48).
    {
        dim3 block(64, 4, 1);
        dim3 grid(4, 512 / 4, NC);
        gpyr_once<1024, 1024, true><<<grid, block, 0, stream>>>(im, out0, out1);
    }
    // Level 2: grid (2, 64, 48).
    {
        dim3 block(64, 4, 1);
        dim3 grid(2, 256 / 4, NC);
        gpyr_once<512, 512, false><<<grid, block, 0, stream>>>(out1, nullptr, out2);
    }
    // Level 3: grid (1, 32, 48).
    {
        dim3 block(64, 4, 1);
        dim3 grid(1, 128 / 4, NC);
        gpyr_once<256, 256, false><<<grid, block, 0, stream>>>(out2, nullptr, out3);
    }
}

// Round 19
// 126.789 us; speedup vs baseline: 4.9554x; 4.9554x over previous
//
#include <hip/hip_runtime.h>

// Gaussian pyramid, 4 levels. Input (16,3,1024,1024) f32.
// R19 = exact revert to the R11 champion (126.0 us): sliding window,
// 4 px/lane, remap-once edge handling, explicit 1-iter prefetch, fused
// level-0 copy. Last 7 redesigns all regressed (struct-heavy variants
// trigger scratch-backed phantom HBM writes); this is the measured best.

struct Row { float4 A, B, C, D; };

template <int WIN>
__device__ __forceinline__ Row loadrow(const float* ip, int iy, int xb) {
    const float4* p = (const float4*)(ip + (size_t)iy * WIN + xb);
    Row r; r.A = p[0]; r.B = p[1]; r.C = p[2]; r.D = p[3];
    return r;
}

// In-place remap so that INTERIOR register wiring is correct at image edges
// (replicate padding). left: virtual window = [bcast(A.x), A, B, C];
// right: [B, C, D, bcast(D.w)]. Only components consumed downstream are
// remapped (A.z, A.w, B.*, C.*, D.x).
__device__ __forceinline__ void remap(Row& w, bool l, bool r) {
    const float4 A = w.A, B = w.B, C = w.C, D = w.D;
    w.A.z = l ? A.x : (r ? B.z : A.z);
    w.A.w = l ? A.x : (r ? B.w : A.w);
    w.B.x = l ? A.x : (r ? C.x : B.x);
    w.B.y = l ? A.y : (r ? C.y : B.y);
    w.B.z = l ? A.z : (r ? C.z : B.z);
    w.B.w = l ? A.w : (r ? C.w : B.w);
    w.C.x = l ? B.x : (r ? D.x : C.x);
    w.C.y = l ? B.y : (r ? D.y : C.y);
    w.C.z = l ? B.z : (r ? D.z : C.z);
    w.C.w = l ? B.w : (r ? D.w : C.w);
    w.D.x = l ? C.x : (r ? D.w : D.x);
}

// Select-free horizontal 5-tap (stride-2 phase) on a remapped row.
__device__ __forceinline__ float4 hconv(const Row& w) {
    const float k0 = 0.0625f, k1 = 0.25f, k2 = 0.375f;
    float4 h;
    h.x = k0 * (w.A.z + w.B.z) + k1 * (w.A.w + w.B.y) + k2 * w.B.x;
    h.y = k0 * (w.B.x + w.C.x) + k1 * (w.B.y + w.B.w) + k2 * w.B.z;
    h.z = k0 * (w.B.z + w.C.z) + k1 * (w.B.w + w.C.y) + k2 * w.C.x;
    h.w = k0 * (w.C.x + w.D.x) + k1 * (w.C.y + w.C.w) + k2 * w.C.z;
    return h;
}

template <int R, int HIN, int WIN, bool FUSE>
__global__ __launch_bounds__(256) void gpyr_slide(
        const float* __restrict__ in,
        float* __restrict__ out0,
        float* __restrict__ out1) {
    constexpr int HOUT = HIN / 2, WOUT = WIN / 2;
    const int tx = threadIdx.x, ty = threadIdx.y;
    const int ox0 = (blockIdx.x * blockDim.x + tx) * 4;
    const int Y0  = (blockIdx.y * blockDim.y + ty) * R;
    const int img = blockIdx.z;

    const bool left  = (ox0 == 0);
    const bool right = (2 * ox0 + 12 > WIN);
    int xb = 2 * ox0 - 4;
    if (left)  xb = 0;
    if (right) xb = WIN - 16;

    const float* ip = in + (size_t)img * HIN * WIN;
    float* o1 = out1 + (size_t)img * HOUT * WOUT;
    float* o0 = out0 + (size_t)img * HIN * WIN;

    // Prologue rows + iteration-0 prefetch (all independent -> 5 loads in flight).
    Row r0 = loadrow<WIN>(ip, max(2 * Y0 - 2, 0), xb);
    Row r1 = loadrow<WIN>(ip, max(2 * Y0 - 1, 0), xb);
    Row r2 = loadrow<WIN>(ip, 2 * Y0, xb);
    Row ra = loadrow<WIN>(ip, 2 * Y0 + 1, xb);
    Row rb = loadrow<WIN>(ip, min(2 * Y0 + 2, HIN - 1), xb);

    remap(r0, left, right); remap(r1, left, right); remap(r2, left, right);
    float4 hs0 = hconv(r0), hs1 = hconv(r1), hs2 = hconv(r2);
    float4 qlo = r2.B, qhi = r2.C;   // pending copy data for even input row 2*Y0

    const float k0 = 0.0625f, k1 = 0.25f, k2 = 0.375f;

#pragma unroll
    for (int i = 0; i < R; ++i) {
        const int oy = Y0 + i;

        // Prefetch NEXT iteration's rows before consuming the current ones.
        Row ran, rbn;
        if (i + 1 < R) {
            ran = loadrow<WIN>(ip, 2 * (oy + 1) + 1, xb);                 // 2oy+3 <= HIN-1
            rbn = loadrow<WIN>(ip, min(2 * (oy + 1) + 2, HIN - 1), xb);
        }

        remap(ra, left, right);
        remap(rb, left, right);

        if (FUSE) {
            float* op = o0 + (size_t)(2 * oy) * WIN + 2 * ox0;
            *(float4*)(op)     = qlo;
            *(float4*)(op + 4) = qhi;
            float* op1 = o0 + (size_t)(2 * oy + 1) * WIN + 2 * ox0;
            *(float4*)(op1)     = ra.B;
            *(float4*)(op1 + 4) = ra.C;
        }

        float4 ha = hconv(ra), hb = hconv(rb);
        qlo = rb.B; qhi = rb.C;        // row 2*oy+2 = next iteration's even row

        float4 o;
        o.x = k0 * (hs0.x + hb.x) + k1 * (hs1.x + ha.x) + k2 * hs2.x;
        o.y = k0 * (hs0.y + hb.y) + k1 * (hs1.y + ha.y) + k2 * hs2.y;
        o.z = k0 * (hs0.z + hb.z) + k1 * (hs1.z + ha.z) + k2 * hs2.z;
        o.w = k0 * (hs0.w + hb.w) + k1 * (hs1.w + ha.w) + k2 * hs2.w;
        *(float4*)(o1 + (size_t)oy * WOUT + ox0) = o;

        hs0 = hs2; hs1 = ha; hs2 = hb;   // slide down 2 input rows
        ra = ran; rb = rbn;
    }
}

extern "C" void kernel_launch(void* const* d_in, const int* in_sizes, int n_in,
                              void* d_out, int out_size, void* d_ws, size_t ws_size,
                              hipStream_t stream) {
    const float* im = (const float*)d_in[0];
    float* out = (float*)d_out;

    const int NC = 16 * 3;
    const size_t L0 = (size_t)NC * 1024 * 1024;
    const size_t L1 = (size_t)NC * 512 * 512;
    const size_t L2 = (size_t)NC * 256 * 256;

    float* out0 = out;
    float* out1 = out0 + L0;
    float* out2 = out1 + L1;
    float* out3 = out2 + L2;

    // Level 0+1 fused: 512x512 out, R=8 rows/thread.
    {
        dim3 block(64, 4, 1);
        dim3 grid(2, 512 / (4 * 8), NC);       // (2, 16, 48)
        gpyr_slide<8, 1024, 1024, true><<<grid, block, 0, stream>>>(im, out0, out1);
    }
    // Level 2: 256x256 out, R=4.
    {
        dim3 block(64, 4, 1);
        dim3 grid(1, 256 / (4 * 4), NC);       // (1, 16, 48)
        gpyr_slide<4, 512, 512, false><<<grid, block, 0, stream>>>(out1, nullptr, out2);
    }
    // Level 3: 128x128 out, R=2.
    {
        dim3 block(32, 8, 1);
        dim3 grid(1, 128 / (8 * 2), NC);       // (1, 8, 48)
        gpyr_slide<2, 256, 256, false><<<grid, block, 0, stream>>>(out2, nullptr, out3);
    }
}